// Round 3
// baseline (137.932 us; speedup 1.0000x reference)
//
#include <hip/hip_runtime.h>
#include <math.h>

// VQ quantizer: x [512,256,12] fp32, codebook [512,12] fp32.
// Outputs (concatenated fp32): quantized_st [512*256*12], indices-as-float [512*256], loss [1].
namespace {
constexpr int KCB   = 512;             // codebook size
constexpr int DIM   = 12;              // latent dim
constexpr int NTOK  = 512 * 256;       // 131072 tokens
constexpr int QSIZE = NTOK * DIM;      // 1572864
constexpr int NSPLIT = 8;              // k-chunks (one wave each)
constexpr int KCHUNK = KCB / NSPLIT;   // 64 codes per chunk
constexpr int TPT    = 2;              // tokens per thread
constexpr int TOKS_PER_BLOCK = 64 * TPT;         // 128
constexpr int NBLK   = NTOK / TOKS_PER_BLOCK;    // 1024 blocks x 512 threads

// Pack codebook into 16-float (64B) rows: w[0..11], w2, pad. Also zero the
// loss slot (harness re-poisons d_out to 0xAA before every launch).
__global__ __launch_bounds__(256) void pack_cb(const float* __restrict__ cb,
                                               float* __restrict__ pk,
                                               float* __restrict__ out) {
    int k = blockIdx.x * blockDim.x + threadIdx.x;
    if (k == 0) out[QSIZE + NTOK] = 0.f;
    if (k >= KCB) return;
    float w[DIM];
#pragma unroll
    for (int d = 0; d < DIM; ++d) w[d] = cb[k * DIM + d];
    float w2 = 0.f;
#pragma unroll
    for (int d = 0; d < DIM; ++d) w2 += w[d] * w[d];
#pragma unroll
    for (int d = 0; d < DIM; ++d) pk[k * 16 + d] = w[d];
    pk[k * 16 + 12] = w2;
    pk[k * 16 + 13] = 0.f;
    pk[k * 16 + 14] = 0.f;
    pk[k * 16 + 15] = 0.f;
}

// 12-term dot + score, EXACT fmaf sequence validated in rounds 1-2 (absmax 0.0
// vs numpy). Do not reorder.
__device__ inline void code_score(const float (&xv)[DIM], float x2,
                                  const float4& c0, const float4& c1,
                                  const float4& c2, const float4& c3,
                                  float& dsc) {
    float xw = 0.f;
    xw = fmaf(xv[0],  c0.x, xw);
    xw = fmaf(xv[1],  c0.y, xw);
    xw = fmaf(xv[2],  c0.z, xw);
    xw = fmaf(xv[3],  c0.w, xw);
    xw = fmaf(xv[4],  c1.x, xw);
    xw = fmaf(xv[5],  c1.y, xw);
    xw = fmaf(xv[6],  c1.z, xw);
    xw = fmaf(xv[7],  c1.w, xw);
    xw = fmaf(xv[8],  c2.x, xw);
    xw = fmaf(xv[9],  c2.y, xw);
    xw = fmaf(xv[10], c2.z, xw);
    xw = fmaf(xv[11], c2.w, xw);
    dsc = fmaf(-2.f, xw, x2) + c3.x;   // c3.x = w2[k]
}

// Block = 128 tokens x 8 k-splits (512 threads). Wave s scans codes
// [s*64,(s+1)*64) for 2 tokens/thread. Codebook reads go through per-lane
// VMEM (all 64 lanes -> same 64B line -> one L1 transaction, broadcast) with
// an opaque divergent base so the compiler can't re-scalarize to s_load —
// VMEM has precise in-order vmcnt the compiler pipelines; SMEM does not.
__global__ __launch_bounds__(512, 4) void vq_main(const float* __restrict__ x,
                                                  const float* __restrict__ cb,
                                                  const float4* __restrict__ pk,
                                                  float* __restrict__ out) {
    const int tid  = threadIdx.x;
    const int lane = tid & 63;
    const int s = __builtin_amdgcn_readfirstlane(tid >> 6);  // k-split id, wave-uniform
    const int tA = blockIdx.x * TOKS_PER_BLOCK + lane;       // token for j=0
    const int tB = tA + 64;                                  // token for j=1

    // opaque divergent zero: forces the codebook loads onto the VMEM pipe
    int dz;
    asm volatile("v_mov_b32 %0, 0" : "=v"(dz));
    const float4* pkd = pk + (size_t)(unsigned)dz;

    const float4* xpA = (const float4*)(x + (size_t)tA * DIM);
    const float4* xpB = (const float4*)(x + (size_t)tB * DIM);
    float4 a0 = xpA[0], a1 = xpA[1], a2 = xpA[2];
    float4 b0 = xpB[0], b1 = xpB[1], b2 = xpB[2];
    float xsA[DIM] = {a0.x, a0.y, a0.z, a0.w, a1.x, a1.y, a1.z, a1.w,
                      a2.x, a2.y, a2.z, a2.w};
    float xsB[DIM] = {b0.x, b0.y, b0.z, b0.w, b1.x, b1.y, b1.z, b1.w,
                      b2.x, b2.y, b2.z, b2.w};

    float x2A = 0.f, x2B = 0.f;
#pragma unroll
    for (int d = 0; d < DIM; ++d) x2A = fmaf(xsA[d], xsA[d], x2A);
#pragma unroll
    for (int d = 0; d < DIM; ++d) x2B = fmaf(xsB[d], xsB[d], x2B);

    float bestA = INFINITY, bestB = INFINITY;
    int biA = 0, biB = 0;
    const int k0 = s * KCHUNK;
    const float4* cp = pkd + (size_t)k0 * 4;
#pragma unroll 2
    for (int kk = 0; kk < KCHUNK; ++kk) {
        float4 c0 = cp[0], c1 = cp[1], c2 = cp[2], c3 = cp[3];
        cp += 4;
        const int k = k0 + kk;
        float dA, dB;
        code_score(xsA, x2A, c0, c1, c2, c3, dA);
        code_score(xsB, x2B, c0, c1, c2, c3, dB);
        bool cA = dA < bestA;                 // strict < => first occurrence
        bestA = cA ? dA : bestA;
        biA   = cA ? k : biA;
        bool cB = dB < bestB;
        bestB = cB ? dB : bestB;
        biB   = cB ? k : biB;
    }

    // pack (score,k) -> u64 so unsigned-min == lexicographic (score,k) min
    auto mkkey = [](float v, int k) {
        unsigned su = __float_as_uint(v);
        su = (su & 0x80000000u) ? ~su : (su | 0x80000000u);
        return ((unsigned long long)su << 32) | (unsigned)k;
    };
    __shared__ unsigned long long red[NSPLIT][TOKS_PER_BLOCK];
    red[s][lane]      = mkkey(bestA, biA);
    red[s][64 + lane] = mkkey(bestB, biB);
    __syncthreads();

    // wave s in {0,1} finalizes token s*64+lane — exactly the token whose xs
    // this thread already holds (xsA for s=0, xsB for s=1).
    if (s < TPT) {
        const int tok = s * 64 + lane;
        unsigned long long m = red[0][tok];
#pragma unroll
        for (int r = 1; r < NSPLIT; ++r) {
            unsigned long long v = red[r][tok];
            m = v < m ? v : m;
        }
        const int bid = (int)(m & 0xffffffffULL);
        unsigned eu = (unsigned)(m >> 32);
        unsigned orig = (eu & 0x80000000u) ? (eu ^ 0x80000000u) : ~eu;
        const float bsc = __uint_as_float(orig);
        const int t = blockIdx.x * TOKS_PER_BLOCK + tok;

        const float4* wrow = (const float4*)(cb + (size_t)bid * DIM);
        float4 q0 = wrow[0], q1 = wrow[1], q2 = wrow[2];
        float qs[DIM] = {q0.x, q0.y, q0.z, q0.w, q1.x, q1.y, q1.z, q1.w,
                         q2.x, q2.y, q2.z, q2.w};

        auto emit = [&](const float (&xv)[DIM]) {
            float4* qo = (float4*)(out + (size_t)t * DIM);
            float4 r0, r1, r2;
            r0.x = xv[0] + (qs[0] - xv[0]);    r0.y = xv[1] + (qs[1] - xv[1]);
            r0.z = xv[2] + (qs[2] - xv[2]);    r0.w = xv[3] + (qs[3] - xv[3]);
            r1.x = xv[4] + (qs[4] - xv[4]);    r1.y = xv[5] + (qs[5] - xv[5]);
            r1.z = xv[6] + (qs[6] - xv[6]);    r1.w = xv[7] + (qs[7] - xv[7]);
            r2.x = xv[8] + (qs[8] - xv[8]);    r2.y = xv[9] + (qs[9] - xv[9]);
            r2.z = xv[10] + (qs[10] - xv[10]); r2.w = xv[11] + (qs[11] - xv[11]);
            qo[0] = r0; qo[1] = r1; qo[2] = r2;
        };
        if (s == 0) emit(xsA); else emit(xsB);

        out[QSIZE + t] = (float)bid;

        // loss: sum_d(q-x)^2 == best score (~1e-8 rel apart; threshold ~2%)
        float ls = bsc * (1.25f / (float)QSIZE);
#pragma unroll
        for (int off = 32; off > 0; off >>= 1) ls += __shfl_down(ls, off);
        if (lane == 0) atomicAdd(out + QSIZE + NTOK, ls);
    }
}
} // namespace

extern "C" void kernel_launch(void* const* d_in, const int* in_sizes, int n_in,
                              void* d_out, int out_size, void* d_ws, size_t ws_size,
                              hipStream_t stream) {
    const float* x  = (const float*)d_in[0];
    const float* cb = (const float*)d_in[1];
    float* out = (float*)d_out;
    float* pk  = (float*)d_ws;   // 512*16*4 = 32 KiB workspace

    pack_cb<<<2, 256, 0, stream>>>(cb, pk, out);
    vq_main<<<NBLK, 512, 0, stream>>>(x, cb, (const float4*)pk, out);
}

// Round 4
// 108.382 us; speedup vs baseline: 1.2726x; 1.2726x over previous
//
#include <hip/hip_runtime.h>
#include <math.h>

// VQ quantizer: x [512,256,12] fp32, codebook [512,12] fp32.
// Outputs (concatenated fp32): quantized_st [512*256*12], indices-as-float [512*256], loss [1].
namespace {
constexpr int KCB   = 512;
constexpr int DIM   = 12;
constexpr int NTOK  = 512 * 256;       // 131072
constexpr int QSIZE = NTOK * DIM;      // 1572864
constexpr int NSPLIT = 8;              // k-chunks, one wave each
constexpr int KCHUNK = KCB / NSPLIT;   // 64
constexpr int TPT    = 2;              // tokens per thread
constexpr int TOKS_PER_BLOCK = 64 * TPT;        // 128
constexpr int NBLK   = NTOK / TOKS_PER_BLOCK;   // 1024 blocks x 512 thr
constexpr int WVEC_FLOATS = KCB * DIM;          // 6144 (tight 48B rows)
constexpr int CB_FLOATS   = WVEC_FLOATS + KCB;  // + w2[512] = 6656
constexpr int CB_F4       = CB_FLOATS / 4;      // 1664 float4 to stage

// ws layout: [wvec 512x12 tight][w2 512]. Also zero the loss slot.
__global__ __launch_bounds__(256) void pack_cb(const float* __restrict__ cb,
                                               float* __restrict__ ws,
                                               float* __restrict__ out) {
    int k = blockIdx.x * blockDim.x + threadIdx.x;
    if (k == 0) out[QSIZE + NTOK] = 0.f;
    if (k >= KCB) return;
    float w[DIM];
#pragma unroll
    for (int d = 0; d < DIM; ++d) w[d] = cb[k * DIM + d];
    float w2 = 0.f;
#pragma unroll
    for (int d = 0; d < DIM; ++d) w2 += w[d] * w[d];   // same rounding as rounds 1-3
#pragma unroll
    for (int d = 0; d < DIM; ++d) ws[k * DIM + d] = w[d];
    ws[WVEC_FLOATS + k] = w2;
}

// EXACT score sequence validated rounds 1-3 (absmax 0.0 vs numpy). Do not reorder.
__device__ inline float code_score(const float (&xv)[DIM], float x2,
                                   const float4& c0, const float4& c1,
                                   const float4& c2, float w2k) {
    float xw = 0.f;
    xw = fmaf(xv[0],  c0.x, xw);
    xw = fmaf(xv[1],  c0.y, xw);
    xw = fmaf(xv[2],  c0.z, xw);
    xw = fmaf(xv[3],  c0.w, xw);
    xw = fmaf(xv[4],  c1.x, xw);
    xw = fmaf(xv[5],  c1.y, xw);
    xw = fmaf(xv[6],  c1.z, xw);
    xw = fmaf(xv[7],  c1.w, xw);
    xw = fmaf(xv[8],  c2.x, xw);
    xw = fmaf(xv[9],  c2.y, xw);
    xw = fmaf(xv[10], c2.z, xw);
    xw = fmaf(xv[11], c2.w, xw);
    return fmaf(-2.f, xw, x2) + w2k;
}

// Block = 128 tokens x 8 k-splits (512 thr). Codebook staged in LDS once per
// block; same-address wave reads are HW broadcast (conflict-free) with
// fine-grained lgkmcnt pipelining — fixes round-2's scalar-K$ thrash and
// round-3's L1-return serialization. launch_bounds(512,8): VGPR<=64 so 4
// blocks/CU (32 waves) fit.
__global__ __launch_bounds__(512, 8) void vq_main(const float* __restrict__ x,
                                                  const float* __restrict__ cb,
                                                  const float* __restrict__ pk,
                                                  float* __restrict__ out) {
    __shared__ float lds[CB_FLOATS];   // 26624 B; aliased for argmin reduction later
    const int tid  = threadIdx.x;
    const int lane = tid & 63;
    const int s = __builtin_amdgcn_readfirstlane(tid >> 6);  // k-split id
    const int tA = blockIdx.x * TOKS_PER_BLOCK + lane;
    const int tB = tA + 64;

    // stage codebook global->LDS (coalesced float4), overlapped with x loads
    {
        float4* l4 = (float4*)lds;
        const float4* g4 = (const float4*)pk;
        for (int i = tid; i < CB_F4; i += 512) l4[i] = g4[i];
    }

    const float4* xpA = (const float4*)(x + (size_t)tA * DIM);
    const float4* xpB = (const float4*)(x + (size_t)tB * DIM);
    float4 a0 = xpA[0], a1 = xpA[1], a2 = xpA[2];
    float4 b0 = xpB[0], b1 = xpB[1], b2 = xpB[2];
    float xsA[DIM] = {a0.x, a0.y, a0.z, a0.w, a1.x, a1.y, a1.z, a1.w,
                      a2.x, a2.y, a2.z, a2.w};
    float xsB[DIM] = {b0.x, b0.y, b0.z, b0.w, b1.x, b1.y, b1.z, b1.w,
                      b2.x, b2.y, b2.z, b2.w};
    float x2A = 0.f, x2B = 0.f;
#pragma unroll
    for (int d = 0; d < DIM; ++d) x2A = fmaf(xsA[d], xsA[d], x2A);
#pragma unroll
    for (int d = 0; d < DIM; ++d) x2B = fmaf(xsB[d], xsB[d], x2B);

    __syncthreads();   // codebook resident

    float bestA = INFINITY, bestB = INFINITY;
    int biA = 0, biB = 0;
    const int k0 = s * KCHUNK;
    const float* w2v = lds + WVEC_FLOATS;
#pragma unroll 2
    for (int g = 0; g < KCHUNK / 4; ++g) {     // 16 groups of 4 codes
        // one b128 fetches w2 for 4 codes -> 3.25 LDS reads/code
        float4 w2q = ((const float4*)w2v)[(k0 >> 2) + g];
        const float* cbase = lds + (size_t)(k0 + 4 * g) * DIM;
#pragma unroll
        for (int u = 0; u < 4; ++u) {
            float4 c0 = *(const float4*)(cbase + u * DIM + 0);   // 48B row: 3x b128
            float4 c1 = *(const float4*)(cbase + u * DIM + 4);
            float4 c2 = *(const float4*)(cbase + u * DIM + 8);
            float w2k = (u == 0) ? w2q.x : (u == 1) ? w2q.y : (u == 2) ? w2q.z : w2q.w;
            const int k = k0 + 4 * g + u;
            float dA = code_score(xsA, x2A, c0, c1, c2, w2k);
            float dB = code_score(xsB, x2B, c0, c1, c2, w2k);
            bool cA = dA < bestA;              // strict < => first occurrence
            bestA = cA ? dA : bestA;
            biA   = cA ? k : biA;
            bool cB = dB < bestB;
            bestB = cB ? dB : bestB;
            biB   = cB ? k : biB;
        }
    }

    // cross-wave argmin: packed u64 (monotone(score), k) unsigned-min == exact
    // lexicographic first-occurrence argmin. Alias LDS (codebook scan is done).
    auto mkkey = [](float v, int k) {
        unsigned su = __float_as_uint(v);
        su = (su & 0x80000000u) ? ~su : (su | 0x80000000u);
        return ((unsigned long long)su << 32) | (unsigned)k;
    };
    __syncthreads();   // everyone done reading codebook before overwrite
    unsigned long long* red = (unsigned long long*)lds;  // [NSPLIT][128] = 8KB
    red[s * TOKS_PER_BLOCK + lane]      = mkkey(bestA, biA);
    red[s * TOKS_PER_BLOCK + 64 + lane] = mkkey(bestB, biB);
    __syncthreads();

    // wave s in {0,1} finalizes token group j=s (whose xs it already holds)
    if (s < TPT) {
        const int tok = s * 64 + lane;
        unsigned long long m = red[tok];
#pragma unroll
        for (int r = 1; r < NSPLIT; ++r) {
            unsigned long long v = red[r * TOKS_PER_BLOCK + tok];
            m = v < m ? v : m;
        }
        const int bid = (int)(m & 0xffffffffULL);
        unsigned eu = (unsigned)(m >> 32);
        unsigned orig = (eu & 0x80000000u) ? (eu ^ 0x80000000u) : ~eu;
        const float bsc = __uint_as_float(orig);
        const int t = blockIdx.x * TOKS_PER_BLOCK + tok;

        const float4* wrow = (const float4*)(cb + (size_t)bid * DIM);
        float4 q0 = wrow[0], q1 = wrow[1], q2 = wrow[2];
        float qs[DIM] = {q0.x, q0.y, q0.z, q0.w, q1.x, q1.y, q1.z, q1.w,
                         q2.x, q2.y, q2.z, q2.w};

        auto emit = [&](const float (&xv)[DIM]) {
            float4* qo = (float4*)(out + (size_t)t * DIM);
            float4 r0, r1, r2;
            r0.x = xv[0] + (qs[0] - xv[0]);    r0.y = xv[1] + (qs[1] - xv[1]);
            r0.z = xv[2] + (qs[2] - xv[2]);    r0.w = xv[3] + (qs[3] - xv[3]);
            r1.x = xv[4] + (qs[4] - xv[4]);    r1.y = xv[5] + (qs[5] - xv[5]);
            r1.z = xv[6] + (qs[6] - xv[6]);    r1.w = xv[7] + (qs[7] - xv[7]);
            r2.x = xv[8] + (qs[8] - xv[8]);    r2.y = xv[9] + (qs[9] - xv[9]);
            r2.z = xv[10] + (qs[10] - xv[10]); r2.w = xv[11] + (qs[11] - xv[11]);
            qo[0] = r0; qo[1] = r1; qo[2] = r2;
        };
        if (s == 0) emit(xsA); else emit(xsB);

        out[QSIZE + t] = (float)bid;

        float ls = bsc * (1.25f / (float)QSIZE);
#pragma unroll
        for (int off = 32; off > 0; off >>= 1) ls += __shfl_down(ls, off);
        if (lane == 0) atomicAdd(out + QSIZE + NTOK, ls);
    }
}
} // namespace

extern "C" void kernel_launch(void* const* d_in, const int* in_sizes, int n_in,
                              void* d_out, int out_size, void* d_ws, size_t ws_size,
                              hipStream_t stream) {
    const float* x  = (const float*)d_in[0];
    const float* cb = (const float*)d_in[1];
    float* out = (float*)d_out;
    float* pk  = (float*)d_ws;   // 26.6 KB workspace

    pack_cb<<<2, 256, 0, stream>>>(cb, pk, out);
    vq_main<<<NBLK, 512, 0, stream>>>(x, cb, pk, out);
}